// Round 1
// baseline (1066.559 us; speedup 1.0000x reference)
//
#include <hip/hip_runtime.h>
#include <cstdint>
#include <cstddef>

#define NHEAD 4
#define HID 64
#define NCOL 256          // NHEAD*HID
#define INDIM 128
#define PREDDIM 16
#define RELNUM 50
#define NLAYER 3
#define MLP_TILE 16
#define SCAN_CHUNK 1024

// ---------------- node scoring MLP ----------------
// h0[n,k] = sum_j relu(dot(X[n,:],W1[k,j,:]) + b1[k,j]) * W2[k,j] + b2[k]
// One thread per column c = k*64+j, W1 row held in VGPRs; node-tile addresses
// are block-uniform -> scalar loads. Wave w == head w (c = w*64 + lane).
__global__ __launch_bounds__(256, 2) void mlp_kernel(
    const float* __restrict__ X, const float* __restrict__ W1,
    const float* __restrict__ b1, const float* __restrict__ W2,
    const float* __restrict__ b2, float* __restrict__ h0, int N)
{
    const int c = threadIdx.x;          // 0..255
    const int k = c >> 6;               // head
    float w[INDIM];
    {
        const float4* W4 = reinterpret_cast<const float4*>(W1) + (size_t)c * (INDIM / 4);
        #pragma unroll
        for (int i = 0; i < INDIM / 4; i++) {
            float4 v = W4[i];
            w[4*i+0] = v.x; w[4*i+1] = v.y; w[4*i+2] = v.z; w[4*i+3] = v.w;
        }
    }
    const float bb = b1[c];
    const float w2 = W2[c];
    const float bk = b2[k];

    for (int n0 = blockIdx.x * MLP_TILE; n0 < N; n0 += gridDim.x * MLP_TILE) {
        const int nmax = min(MLP_TILE, N - n0);
        for (int n = 0; n < nmax; n++) {
            const float4* A4 = reinterpret_cast<const float4*>(X) + (size_t)(n0 + n) * (INDIM / 4);
            float a0 = 0.f, a1 = 0.f, a2 = 0.f, a3 = 0.f;
            #pragma unroll
            for (int i = 0; i < INDIM / 4; i++) {
                float4 av = A4[i];              // block-uniform -> s_load
                a0 = fmaf(w[4*i+0], av.x, a0);
                a1 = fmaf(w[4*i+1], av.y, a1);
                a2 = fmaf(w[4*i+2], av.z, a2);
                a3 = fmaf(w[4*i+3], av.w, a3);
            }
            float acc = bb + ((a0 + a1) + (a2 + a3));
            float v = fmaxf(acc, 0.f) * w2;
            // sum over 64 lanes of this wave (= over j for head k)
            #pragma unroll
            for (int off = 32; off >= 1; off >>= 1) v += __shfl_down(v, off);
            if ((c & 63) == 0) h0[(size_t)(n0 + n) * NHEAD + k] = v + bk;
        }
    }
}

// ---------------- attention weight table ----------------
// wtab[l][t][h] = exp(leaky_relu(dot(rel_emb[t,:], W_pred[l,:,h]), 0.2))
__global__ void table_kernel(const float* __restrict__ rel_emb,
                             const float* __restrict__ W_pred,
                             float* __restrict__ wtab)
{
    int idx = blockIdx.x * blockDim.x + threadIdx.x;
    if (idx >= NLAYER * RELNUM * NHEAD) return;
    int h = idx & 3;
    int q = idx >> 2;
    int t = q % RELNUM;
    int l = q / RELNUM;
    float acc = 0.f;
    #pragma unroll
    for (int p = 0; p < PREDDIM; p++)
        acc = fmaf(rel_emb[t * PREDDIM + p], W_pred[l * PREDDIM * NHEAD + p * NHEAD + h], acc);
    float e = (acc >= 0.f) ? acc : 0.2f * acc;
    wtab[idx] = __expf(e) ; // fast exp; |e| small
}

// ---------------- CSR build ----------------
__global__ void count_kernel(const int* __restrict__ dst, int* __restrict__ deg, int E)
{
    int e = blockIdx.x * blockDim.x + threadIdx.x;
    if (e < E) atomicAdd(&deg[dst[e]], 1);
}

__global__ void blocksum_kernel(const int* __restrict__ deg, int* __restrict__ partials, int N)
{
    __shared__ int lds[256];
    int t = threadIdx.x;
    int base = blockIdx.x * SCAN_CHUNK + t * 4;
    int s = 0;
    #pragma unroll
    for (int e = 0; e < 4; e++) { int i = base + e; if (i < N) s += deg[i]; }
    lds[t] = s; __syncthreads();
    for (int off = 128; off >= 1; off >>= 1) {
        if (t < off) lds[t] += lds[t + off];
        __syncthreads();
    }
    if (t == 0) partials[blockIdx.x] = lds[0];
}

__global__ void scanpart_kernel(int* __restrict__ partials, int NB)
{
    if (blockIdx.x == 0 && threadIdx.x == 0) {
        int run = 0;
        for (int i = 0; i < NB; i++) { int v = partials[i]; partials[i] = run; run += v; }
    }
}

__global__ void scanfinal_kernel(const int* __restrict__ deg, const int* __restrict__ partials,
                                 int* __restrict__ row_start, int* __restrict__ cursor, int N)
{
    __shared__ int lds[256];
    int t = threadIdx.x;
    int base = blockIdx.x * SCAN_CHUNK + t * 4;
    int s = 0;
    #pragma unroll
    for (int e = 0; e < 4; e++) { int i = base + e; if (i < N) s += deg[i]; }
    lds[t] = s; __syncthreads();
    if (t == 0) {
        int run = partials[blockIdx.x];
        for (int i = 0; i < 256; i++) { int v = lds[i]; lds[i] = run; run += v; }
    }
    __syncthreads();
    int off = lds[t];
    #pragma unroll
    for (int e = 0; e < 4; e++) {
        int i = base + e;
        if (i < N) { row_start[i] = off; cursor[i] = off; off += deg[i]; }
    }
}

// pack src (17 bits, N<131072) | type (6 bits, <64) << 17
__global__ void scatter_kernel(const int* __restrict__ src, const int* __restrict__ dst,
                               const int* __restrict__ types, int* __restrict__ cursor,
                               int* __restrict__ sorted, int E)
{
    int e = blockIdx.x * blockDim.x + threadIdx.x;
    if (e < E) {
        int d = dst[e];
        int p = atomicAdd(&cursor[d], 1);
        sorted[p] = src[e] | (types[e] << 17);
    }
}

// ---------------- per-layer aggregation ----------------
// thread = (dst, head). MODE 0: hin is (N,4); MODE 1: hin is (N,); both write
// scalar mean(relu(num/den)). MODE 2: fuse centrality scaling + final leaky.
template <int MODE>
__global__ __launch_bounds__(256) void agg_kernel(
    const int* __restrict__ row_start, const int* __restrict__ deg,
    const int* __restrict__ sorted, const float* __restrict__ wt_l,
    const float* __restrict__ hin, float* __restrict__ hout,
    const float* __restrict__ centrality, const float* __restrict__ gamma,
    const float* __restrict__ beta, int N)
{
    __shared__ float wt[RELNUM * NHEAD];
    for (int i = threadIdx.x; i < RELNUM * NHEAD; i += blockDim.x) wt[i] = wt_l[i];
    __syncthreads();

    int gid = blockIdx.x * blockDim.x + threadIdx.x;
    int d = gid >> 2, h = gid & 3;
    if (d >= N) return;

    int b = row_start[d], n = deg[d];
    float num = 0.f, den = 0.f;
    for (int i = 0; i < n; i++) {
        int pk = sorted[b + i];                 // same addr across the quad
        int s = pk & 0x1FFFF;
        int t = pk >> 17;
        float wv = wt[t * NHEAD + h];
        float hv = (MODE == 0) ? hin[(size_t)s * NHEAD + h] : hin[s];
        num = fmaf(wv, hv, num);
        den += wv;
    }
    float r = (n > 0) ? fmaxf(num / den, 0.f) : 0.f;   // relu(segsum(a*h))
    if (MODE == 2) r = (centrality[d] * gamma[h] + beta[h]) * r;
    // mean over the 4 heads (quad of lanes)
    r += __shfl_xor(r, 1);
    r += __shfl_xor(r, 2);
    r *= 0.25f;
    if (h == 0) {
        if (MODE < 2) hout[d] = r;
        else          hout[d] = (r > 0.f) ? r : 0.01f * r;
    }
}

// ---------------- launch ----------------
extern "C" void kernel_launch(void* const* d_in, const int* in_sizes, int n_in,
                              void* d_out, int out_size, void* d_ws, size_t ws_size,
                              hipStream_t stream)
{
    const float* X          = (const float*)d_in[0];
    const float* centrality = (const float*)d_in[1];
    const float* W1         = (const float*)d_in[2];
    const float* b1         = (const float*)d_in[3];
    const float* W2         = (const float*)d_in[4];
    const float* b2         = (const float*)d_in[5];
    const float* rel_emb    = (const float*)d_in[6];
    const float* W_pred     = (const float*)d_in[7];
    const float* gamma      = (const float*)d_in[8];
    const float* beta       = (const float*)d_in[9];
    const int*   edge_types = (const int*)d_in[10];
    const int*   src        = (const int*)d_in[11];
    const int*   dst        = (const int*)d_in[12];
    float* out = (float*)d_out;

    const int N = in_sizes[1];
    const int E = in_sizes[10];

    char* ws = (char*)d_ws;
    size_t off = 0;
    auto alloc = [&](size_t bytes) -> void* {
        void* p = ws + off;
        off = (off + bytes + 255) & ~(size_t)255;
        return p;
    };
    int*   deg       = (int*)alloc((size_t)N * 4);
    int*   row_start = (int*)alloc((size_t)N * 4);
    int*   cursor    = (int*)alloc((size_t)N * 4);
    int*   partials  = (int*)alloc(4096);
    int*   sorted    = (int*)alloc((size_t)E * 4);
    float* wtab      = (float*)alloc((size_t)NLAYER * RELNUM * NHEAD * 4);
    float* h0        = (float*)alloc((size_t)N * NHEAD * 4);
    float* hs        = (float*)alloc((size_t)N * 4);
    float* hs2       = (float*)alloc((size_t)N * 4);
    (void)ws_size; (void)n_in; (void)out_size;

    hipMemsetAsync(deg, 0, (size_t)N * 4, stream);

    const int eb = (E + 255) / 256;
    const int NB = (N + SCAN_CHUNK - 1) / SCAN_CHUNK;
    count_kernel<<<eb, 256, 0, stream>>>(dst, deg, E);
    blocksum_kernel<<<NB, 256, 0, stream>>>(deg, partials, N);
    scanpart_kernel<<<1, 64, 0, stream>>>(partials, NB);
    scanfinal_kernel<<<NB, 256, 0, stream>>>(deg, partials, row_start, cursor, N);
    scatter_kernel<<<eb, 256, 0, stream>>>(src, dst, edge_types, cursor, sorted, E);

    table_kernel<<<(NLAYER * RELNUM * NHEAD + 255) / 256, 256, 0, stream>>>(rel_emb, W_pred, wtab);
    mlp_kernel<<<512, 256, 0, stream>>>(X, W1, b1, W2, b2, h0, N);

    const int ab = (N * NHEAD + 255) / 256;
    agg_kernel<0><<<ab, 256, 0, stream>>>(row_start, deg, sorted, wtab + 0 * RELNUM * NHEAD,
                                          h0, hs, nullptr, nullptr, nullptr, N);
    agg_kernel<1><<<ab, 256, 0, stream>>>(row_start, deg, sorted, wtab + 1 * RELNUM * NHEAD,
                                          hs, hs2, nullptr, nullptr, nullptr, N);
    agg_kernel<2><<<ab, 256, 0, stream>>>(row_start, deg, sorted, wtab + 2 * RELNUM * NHEAD,
                                          hs2, out, centrality, gamma, beta, N);
}